// Round 9
// baseline (88.406 us; speedup 1.0000x reference)
//
#include <hip/hip_runtime.h>

#define NPTS 16384
#define NNBR 32
#define CIN 16
#define COUT 16
#define NBASIS 16

// LDS f16 row stride 264 (528 B = 132 dw ≡ 4 mod 32): b128 reads alias 2-way (free).
#define WF_OS 264
#define ML_PS 264

// sqrt(10 * log2(e)) : exp(-10 d^2) == exp2(-(SCL*d)^2)
#define RSCL 3.7982825f

// PROBE: run conv body 3x (idempotent). Δdur/2 = conv exec time; if conv is
// exec-bound it surfaces in rocprof top-5 with its own counters.
#define REPS 3

typedef _Float16 half8 __attribute__((ext_vector_type(8)));
typedef _Float16 half4 __attribute__((ext_vector_type(4)));
typedef unsigned short ushort8 __attribute__((ext_vector_type(8)));
typedef float floatx4 __attribute__((ext_vector_type(4)));

// ws layout (f16 units): [0, NPTS*16) xT16 [n][i] ; then Wf16 [o][b*16+i]
#define WS_XT 0
#define WS_WF (NPTS * CIN)

// Prep: 256 blocks x 256 threads (R6-identical).
__global__ __launch_bounds__(256) void prep_kernel(
        const float* __restrict__ input, const float* __restrict__ W,
        _Float16* __restrict__ ws) {
    const int p4 = threadIdx.x >> 2;          // 0..63 point within block
    const int c4 = threadIdx.x & 3;           // channel quad
    const int n = blockIdx.x * 64 + p4;
    half4 v;
    #pragma unroll
    for (int j = 0; j < 4; ++j)
        v[j] = (_Float16)input[(c4 * 4 + j) * NPTS + n];
    *(half4*)&ws[WS_XT + n * CIN + c4 * 4] = v;
    if (blockIdx.x == 0) {   // W -> [o][b*16+i] f16
        const int o = threadIdx.x >> 4, b = threadIdx.x & 15;
        _Float16 w[16];
        #pragma unroll
        for (int i = 0; i < CIN; ++i) w[i] = (_Float16)W[o * 256 + i * 16 + b];
        *(half8*)&ws[WS_WF + o * 256 + b * 16]     = *(half8*)&w[0];
        *(half8*)&ws[WS_WF + o * 256 + b * 16 + 8] = *(half8*)&w[8];
    }
}

// Conv: R6-identical single-barrier body, repeated REPS times. Each rep
// re-executes ALL loads (opaque-zero offset defeats cross-rep CSE) and
// rewrites identical results -> idempotent, absmax unchanged.
__global__ __launch_bounds__(256, 8) void se3_conv_kernel(
        const _Float16* __restrict__ ws,
        const float* __restrict__ coords,    // (NPTS, 3)
        const float* __restrict__ centers,   // (NBASIS,)
        const float* __restrict__ mask,      // (NPTS, NNBR) f32
        const int* __restrict__ neighbors,   // (NPTS, NNBR)
        float* __restrict__ out) {           // (COUT, NPTS)
    __shared__ _Float16 Wf[COUT * WF_OS];        // 8448 B
    __shared__ _Float16 Mld[8 * ML_PS];          // 4224 B
    __shared__ float    rs[8 * NNBR];            // 1024 B  (pre-scaled RSCL)
    __shared__ unsigned short nb16[8 * NNBR];    //  512 B
    __shared__ _Float16 mv16[8 * NNBR];          //  512 B

    const int tid = threadIdx.x;
    const int t = tid & 15;          // lane role (i in B / o in C)
    const int quad = (tid >> 4) & 3; // k-chunk select
    const int wv = tid >> 6;         // wave 0..3
    const int nbase = blockIdx.x * 8;
    const int pt = tid >> 5;
    const int k = tid & 31;

    #pragma unroll 1
    for (int rep = 0; rep < REPS; ++rep) {
        // Opaque zero, regenerated每 rep: compiler cannot prove the addresses
        // equal across reps -> all global loads re-issued each rep.
        int z = 0;
        asm volatile("" : "+v"(z));
        const _Float16* xT16 = &ws[WS_XT] + z;
        const float* coordsz = coords + z;
        const float* maskz = mask + z;
        const int* nbrz = neighbors + z;

        // ---- Phase A loads FIRST: one (pt,k) pair per thread.
        const int n = nbase + pt;
        const int nbr = nbrz[n * NNBR + k] & (NPTS - 1);
        const float m = maskz[n * NNBR + k];
        const float nx = coordsz[n * 3 + 0], ny = coordsz[n * 3 + 1],
                    nz = coordsz[n * 3 + 2];
        const float bx = coordsz[nbr * 3 + 0], by = coordsz[nbr * 3 + 1],
                    bz = coordsz[nbr * 3 + 2];

        // ---- Stage Wf while phase-A loads are in flight.
        {
            const int o = tid >> 4, ch = tid & 15;
            const half8 w0 = *(const half8*)&ws[WS_WF + z + o * 256 + ch * 16];
            const half8 w1 = *(const half8*)&ws[WS_WF + z + o * 256 + ch * 16 + 8];
            *(half8*)&Wf[o * WF_OS + ch * 16]     = w0;
            *(half8*)&Wf[o * WF_OS + ch * 16 + 8] = w1;
        }

        // ---- Phase A compute + intra-wave LDS publish.
        {
            const float dx = bx - nx, dy = by - ny, dz = bz - nz;
            rs[pt * NNBR + k] =
                sqrtf(dx * dx + dy * dy + dz * dz + 1e-12f) * RSCL;
            nb16[pt * NNBR + k] = (unsigned short)nbr;
            mv16[pt * NNBR + k] = (_Float16)m;
        }

        // ---- Phase B: wave wv -> points 2wv, 2wv+1.
        const float cs = centers[t] * RSCL;
        const int kb0 = (wv * 2 + 0) * NNBR + 8 * quad;
        const int kb1 = (wv * 2 + 1) * NNBR + 8 * quad;
        const ushort8 nbv0 = *(const ushort8*)&nb16[kb0];
        const ushort8 nbv1 = *(const ushort8*)&nb16[kb1];
        const half8 mvv0 = *(const half8*)&mv16[kb0];
        const half8 mvv1 = *(const half8*)&mv16[kb1];
        const float4 r00 = *(const float4*)&rs[kb0];
        const float4 r01 = *(const float4*)&rs[kb0 + 4];
        const float4 r10 = *(const float4*)&rs[kb1];
        const float4 r11 = *(const float4*)&rs[kb1 + 4];

        half8 xh0, xh1;
        #pragma unroll
        for (int j = 0; j < 8; ++j) xh0[j] = xT16[(int)nbv0[j] * CIN + t];
        #pragma unroll
        for (int j = 0; j < 8; ++j) xh1[j] = xT16[(int)nbv1[j] * CIN + t];

        const float rj0[8] = {r00.x, r00.y, r00.z, r00.w,
                              r01.x, r01.y, r01.z, r01.w};
        const float rj1[8] = {r10.x, r10.y, r10.z, r10.w,
                              r11.x, r11.y, r11.z, r11.w};

        {   // q = 0
            half8 af, bf;
            #pragma unroll
            for (int j = 0; j < 8; ++j) {
                const float d = rj0[j] - cs;
                bf[j] = (_Float16)__builtin_amdgcn_exp2f(-(d * d));
            }
            af = xh0 * mvv0;
            floatx4 c = {0.0f, 0.0f, 0.0f, 0.0f};
            c = __builtin_amdgcn_mfma_f32_16x16x32_f16(af, bf, c, 0, 0, 0);
            _Float16 h[4];
            #pragma unroll
            for (int v = 0; v < 4; ++v) h[v] = (_Float16)c[v];
            *(uint2*)&Mld[(wv * 2 + 0) * ML_PS + t * 16 + 4 * quad] = *(uint2*)h;
        }
        {   // q = 1
            half8 af, bf;
            #pragma unroll
            for (int j = 0; j < 8; ++j) {
                const float d = rj1[j] - cs;
                bf[j] = (_Float16)__builtin_amdgcn_exp2f(-(d * d));
            }
            af = xh1 * mvv1;
            floatx4 c = {0.0f, 0.0f, 0.0f, 0.0f};
            c = __builtin_amdgcn_mfma_f32_16x16x32_f16(af, bf, c, 0, 0, 0);
            _Float16 h[4];
            #pragma unroll
            for (int v = 0; v < 4; ++v) h[v] = (_Float16)c[v];
            *(uint2*)&Mld[(wv * 2 + 1) * ML_PS + t * 16 + 4 * quad] = *(uint2*)h;
        }

        __syncthreads();   // {Wf, Mld} -> phase C

        // ---- Phase C (every wave, redundant): Out = W(16x256) * Mflat(256x8).
        floatx4 acc = {0.0f, 0.0f, 0.0f, 0.0f};
        #pragma unroll
        for (int cch = 0; cch < 8; ++cch) {
            const int bi = cch * 32 + 8 * quad;
            const half8 a = *(const half8*)&Wf[t * WF_OS + bi];
            half8 b = {};
            if (t < 8) b = *(const half8*)&Mld[t * ML_PS + bi];
            acc = __builtin_amdgcn_mfma_f32_16x16x32_f16(a, b, acc, 0, 0, 0);
        }
        if (t < 8 && wv == (t >> 1)) {
            #pragma unroll
            for (int v = 0; v < 4; ++v)
                out[(4 * quad + v) * NPTS + nbase + t] = acc[v];
        }
        __syncthreads();   // WAR: next rep rewrites Wf/Mld/rs/nb16/mv16
    }
}

extern "C" void kernel_launch(void* const* d_in, const int* in_sizes, int n_in,
                              void* d_out, int out_size, void* d_ws, size_t ws_size,
                              hipStream_t stream) {
    const float* input   = (const float*)d_in[0];
    const float* coords  = (const float*)d_in[1];
    const float* W       = (const float*)d_in[2];
    const float* centers = (const float*)d_in[3];
    const float* mask    = (const float*)d_in[4];
    const int*   nbr     = (const int*)d_in[5];
    float* out = (float*)d_out;
    _Float16* ws = (_Float16*)d_ws;   // ~520 KB of the 256 MB workspace

    prep_kernel<<<NPTS / 64, 256, 0, stream>>>(input, W, ws);
    se3_conv_kernel<<<NPTS / 8, 256, 0, stream>>>(ws, coords, centers, mask,
                                                  nbr, out);
}

// Round 10
// 72.998 us; speedup vs baseline: 1.2111x; 1.2111x over previous
//
#include <hip/hip_runtime.h>

#define NPTS 16384
#define NNBR 32
#define CIN 16
#define COUT 16
#define NBASIS 16

// LDS f16 row stride 264 (528 B = 132 dw ≡ 4 mod 32): b128 reads alias 2-way (free).
#define WF_OS 264
#define ML_PS 264

// sqrt(10 * log2(e)) : exp(-10 d^2) == exp2(-(SCL*d)^2)
#define RSCL 3.7982825f

typedef _Float16 half8 __attribute__((ext_vector_type(8)));
typedef _Float16 half4 __attribute__((ext_vector_type(4)));
typedef unsigned short ushort8 __attribute__((ext_vector_type(8)));
typedef float floatx4 __attribute__((ext_vector_type(4)));

// ws layout (f16 units): [0, NPTS*16) xT16 [n][i] ; then Wf16 [o][b*16+i]
#define WS_XT 0
#define WS_WF (NPTS * CIN)

// Prep: 256 blocks x 256 threads (R6-identical, proven).
__global__ __launch_bounds__(256) void prep_kernel(
        const float* __restrict__ input, const float* __restrict__ W,
        _Float16* __restrict__ ws) {
    const int p4 = threadIdx.x >> 2;          // 0..63 point within block
    const int c4 = threadIdx.x & 3;           // channel quad
    const int n = blockIdx.x * 64 + p4;
    half4 v;
    #pragma unroll
    for (int j = 0; j < 4; ++j)
        v[j] = (_Float16)input[(c4 * 4 + j) * NPTS + n];
    *(half4*)&ws[WS_XT + n * CIN + c4 * 4] = v;
    if (blockIdx.x == 0) {   // W -> [o][b*16+i] f16
        const int o = threadIdx.x >> 4, b = threadIdx.x & 15;
        _Float16 w[16];
        #pragma unroll
        for (int i = 0; i < CIN; ++i) w[i] = (_Float16)W[o * 256 + i * 16 + b];
        *(half8*)&ws[WS_WF + o * 256 + b * 16]     = *(half8*)&w[0];
        *(half8*)&ws[WS_WF + o * 256 + b * 16 + 8] = *(half8*)&w[8];
    }
}

// Conv: 1024 blocks x 256 threads = 16 points/block (TWO 8-point tiles).
// Cold-miss ILP: both tiles' dependent miss chains (nbr -> coords[nbr],
// nb16 -> xT gathers) issue together; tile-B misses drain under tile-A
// compute. 16-pt tiles also make out-writes full 64-B lines and phase C
// fully dense (16 valid cols). LDS 21 KB -> 4 blocks/CU (=1024/256), 16
// waves/CU. Single-barrier structure (R6).
__global__ __launch_bounds__(256, 4) void se3_conv_kernel(
        const _Float16* __restrict__ ws,
        const float* __restrict__ coords,    // (NPTS, 3)
        const float* __restrict__ centers,   // (NBASIS,)
        const float* __restrict__ mask,      // (NPTS, NNBR) f32
        const int* __restrict__ neighbors,   // (NPTS, NNBR)
        float* __restrict__ out) {           // (COUT, NPTS)
    __shared__ _Float16 Wf[COUT * WF_OS];        // 8448 B
    __shared__ _Float16 Mld[16 * ML_PS];         // 8448 B  rows = 16 points
    __shared__ float    rs[16 * NNBR];           // 2048 B  (pre-scaled RSCL)
    __shared__ unsigned short nb16[16 * NNBR];   // 1024 B
    __shared__ _Float16 mv16[16 * NNBR];         // 1024 B

    const _Float16* xT16 = &ws[WS_XT];

    const int tid = threadIdx.x;
    const int t = tid & 15;          // lane role (i in B / o in C)
    const int quad = (tid >> 4) & 3; // k-chunk select
    const int wv = tid >> 6;         // wave 0..3
    const int nbase = blockIdx.x * 16;
    const int pt = tid >> 5;         // 0..7 point-in-tile
    const int k = tid & 31;

    // ---- Phase A loads, BOTH tiles upfront (2x outstanding cold misses).
    const int nA = nbase + pt, nB = nbase + 8 + pt;
    const int nbrA = neighbors[nA * NNBR + k] & (NPTS - 1);
    const int nbrB = neighbors[nB * NNBR + k] & (NPTS - 1);
    const float mA = mask[nA * NNBR + k];
    const float mB = mask[nB * NNBR + k];
    const float nxA = coords[nA * 3 + 0], nyA = coords[nA * 3 + 1],
                nzA = coords[nA * 3 + 2];
    const float nxB = coords[nB * 3 + 0], nyB = coords[nB * 3 + 1],
                nzB = coords[nB * 3 + 2];
    const float bxA = coords[nbrA * 3 + 0], byA = coords[nbrA * 3 + 1],
                bzA = coords[nbrA * 3 + 2];
    const float bxB = coords[nbrB * 3 + 0], byB = coords[nbrB * 3 + 1],
                bzB = coords[nbrB * 3 + 2];

    // ---- Stage Wf while the loads above are in flight (used in phase C).
    {
        const int o = tid >> 4, ch = tid & 15;
        const half8 w0 = *(const half8*)&ws[WS_WF + o * 256 + ch * 16];
        const half8 w1 = *(const half8*)&ws[WS_WF + o * 256 + ch * 16 + 8];
        *(half8*)&Wf[o * WF_OS + ch * 16]     = w0;
        *(half8*)&Wf[o * WF_OS + ch * 16 + 8] = w1;
    }

    // ---- Phase A compute + intra-wave LDS publish (rows 0-7 tile A,
    // 8-15 tile B; producer wave == consumer wave, lgkmcnt-ordered).
    {
        const float dxA = bxA - nxA, dyA = byA - nyA, dzA = bzA - nzA;
        rs[pt * NNBR + k] =
            sqrtf(dxA * dxA + dyA * dyA + dzA * dzA + 1e-12f) * RSCL;
        nb16[pt * NNBR + k] = (unsigned short)nbrA;
        mv16[pt * NNBR + k] = (_Float16)mA;
        const float dxB = bxB - nxB, dyB = byB - nyB, dzB = bzB - nzB;
        rs[(8 + pt) * NNBR + k] =
            sqrtf(dxB * dxB + dyB * dyB + dzB * dzB + 1e-12f) * RSCL;
        nb16[(8 + pt) * NNBR + k] = (unsigned short)nbrB;
        mv16[(8 + pt) * NNBR + k] = (_Float16)mB;
    }

    // ---- Phase B: wave wv -> tile-A rows 2wv,2wv+1 and tile-B rows
    // 8+2wv,8+2wv+1. ALL 32 x-gathers issued before any exp work.
    const float cs = centers[t] * RSCL;
    const int pqA0 = 2 * wv, pqA1 = 2 * wv + 1;
    const int pqB0 = 8 + 2 * wv, pqB1 = 9 + 2 * wv;
    const int kbA0 = pqA0 * NNBR + 8 * quad;
    const int kbA1 = pqA1 * NNBR + 8 * quad;
    const int kbB0 = pqB0 * NNBR + 8 * quad;
    const int kbB1 = pqB1 * NNBR + 8 * quad;
    const ushort8 nvA0 = *(const ushort8*)&nb16[kbA0];
    const ushort8 nvA1 = *(const ushort8*)&nb16[kbA1];
    const ushort8 nvB0 = *(const ushort8*)&nb16[kbB0];
    const ushort8 nvB1 = *(const ushort8*)&nb16[kbB1];

    half8 xA0, xA1, xB0, xB1;
    #pragma unroll
    for (int j = 0; j < 8; ++j) xA0[j] = xT16[(int)nvA0[j] * CIN + t];
    #pragma unroll
    for (int j = 0; j < 8; ++j) xA1[j] = xT16[(int)nvA1[j] * CIN + t];
    #pragma unroll
    for (int j = 0; j < 8; ++j) xB0[j] = xT16[(int)nvB0[j] * CIN + t];
    #pragma unroll
    for (int j = 0; j < 8; ++j) xB1[j] = xT16[(int)nvB1[j] * CIN + t];

    // ---- Tile A compute (B-tile gathers still in flight underneath).
    {
        const half8 mvv = *(const half8*)&mv16[kbA0];
        const float4 r0 = *(const float4*)&rs[kbA0];
        const float4 r1 = *(const float4*)&rs[kbA0 + 4];
        const float rj[8] = {r0.x, r0.y, r0.z, r0.w, r1.x, r1.y, r1.z, r1.w};
        half8 af, bf;
        #pragma unroll
        for (int j = 0; j < 8; ++j) {
            const float d = rj[j] - cs;
            bf[j] = (_Float16)__builtin_amdgcn_exp2f(-(d * d));
        }
        af = xA0 * mvv;
        floatx4 c = {0.0f, 0.0f, 0.0f, 0.0f};
        c = __builtin_amdgcn_mfma_f32_16x16x32_f16(af, bf, c, 0, 0, 0);
        _Float16 h[4];
        #pragma unroll
        for (int v = 0; v < 4; ++v) h[v] = (_Float16)c[v];
        *(uint2*)&Mld[pqA0 * ML_PS + t * 16 + 4 * quad] = *(uint2*)h;
    }
    {
        const half8 mvv = *(const half8*)&mv16[kbA1];
        const float4 r0 = *(const float4*)&rs[kbA1];
        const float4 r1 = *(const float4*)&rs[kbA1 + 4];
        const float rj[8] = {r0.x, r0.y, r0.z, r0.w, r1.x, r1.y, r1.z, r1.w};
        half8 af, bf;
        #pragma unroll
        for (int j = 0; j < 8; ++j) {
            const float d = rj[j] - cs;
            bf[j] = (_Float16)__builtin_amdgcn_exp2f(-(d * d));
        }
        af = xA1 * mvv;
        floatx4 c = {0.0f, 0.0f, 0.0f, 0.0f};
        c = __builtin_amdgcn_mfma_f32_16x16x32_f16(af, bf, c, 0, 0, 0);
        _Float16 h[4];
        #pragma unroll
        for (int v = 0; v < 4; ++v) h[v] = (_Float16)c[v];
        *(uint2*)&Mld[pqA1 * ML_PS + t * 16 + 4 * quad] = *(uint2*)h;
    }
    // ---- Tile B compute.
    {
        const half8 mvv = *(const half8*)&mv16[kbB0];
        const float4 r0 = *(const float4*)&rs[kbB0];
        const float4 r1 = *(const float4*)&rs[kbB0 + 4];
        const float rj[8] = {r0.x, r0.y, r0.z, r0.w, r1.x, r1.y, r1.z, r1.w};
        half8 af, bf;
        #pragma unroll
        for (int j = 0; j < 8; ++j) {
            const float d = rj[j] - cs;
            bf[j] = (_Float16)__builtin_amdgcn_exp2f(-(d * d));
        }
        af = xB0 * mvv;
        floatx4 c = {0.0f, 0.0f, 0.0f, 0.0f};
        c = __builtin_amdgcn_mfma_f32_16x16x32_f16(af, bf, c, 0, 0, 0);
        _Float16 h[4];
        #pragma unroll
        for (int v = 0; v < 4; ++v) h[v] = (_Float16)c[v];
        *(uint2*)&Mld[pqB0 * ML_PS + t * 16 + 4 * quad] = *(uint2*)h;
    }
    {
        const half8 mvv = *(const half8*)&mv16[kbB1];
        const float4 r0 = *(const float4*)&rs[kbB1];
        const float4 r1 = *(const float4*)&rs[kbB1 + 4];
        const float rj[8] = {r0.x, r0.y, r0.z, r0.w, r1.x, r1.y, r1.z, r1.w};
        half8 af, bf;
        #pragma unroll
        for (int j = 0; j < 8; ++j) {
            const float d = rj[j] - cs;
            bf[j] = (_Float16)__builtin_amdgcn_exp2f(-(d * d));
        }
        af = xB1 * mvv;
        floatx4 c = {0.0f, 0.0f, 0.0f, 0.0f};
        c = __builtin_amdgcn_mfma_f32_16x16x32_f16(af, bf, c, 0, 0, 0);
        _Float16 h[4];
        #pragma unroll
        for (int v = 0; v < 4; ++v) h[v] = (_Float16)c[v];
        *(uint2*)&Mld[pqB1 * ML_PS + t * 16 + 4 * quad] = *(uint2*)h;
    }

    __syncthreads();   // the ONLY barrier: {Wf, Mld} -> phase C

    // ---- Phase C (every wave, redundant): Out = W(16x256) * Mflat(256x16).
    // A[m=o=t][bi]; B[bi][n=pt=t] — all 16 cols valid now.
    floatx4 acc = {0.0f, 0.0f, 0.0f, 0.0f};
    #pragma unroll
    for (int cch = 0; cch < 8; ++cch) {
        const int bi = cch * 32 + 8 * quad;
        const half8 a = *(const half8*)&Wf[t * WF_OS + bi];
        const half8 b = *(const half8*)&Mld[t * ML_PS + bi];
        acc = __builtin_amdgcn_mfma_f32_16x16x32_f16(a, b, acc, 0, 0, 0);
    }
    // D[row=o=4quad+v][col=pt=t]; wave wv stores v==wv rows -> 4 full 64-B
    // lines per wave, each (row,col) written exactly once.
    out[(4 * quad + wv) * NPTS + nbase + t] = acc[wv];
}

extern "C" void kernel_launch(void* const* d_in, const int* in_sizes, int n_in,
                              void* d_out, int out_size, void* d_ws, size_t ws_size,
                              hipStream_t stream) {
    const float* input   = (const float*)d_in[0];
    const float* coords  = (const float*)d_in[1];
    const float* W       = (const float*)d_in[2];
    const float* centers = (const float*)d_in[3];
    const float* mask    = (const float*)d_in[4];
    const int*   nbr     = (const int*)d_in[5];
    float* out = (float*)d_out;
    _Float16* ws = (_Float16*)d_ws;   // ~520 KB of the 256 MB workspace

    prep_kernel<<<NPTS / 64, 256, 0, stream>>>(input, W, ws);
    se3_conv_kernel<<<NPTS / 16, 256, 0, stream>>>(ws, coords, centers, mask,
                                                   nbr, out);
}